// Round 12
// baseline (141.520 us; speedup 1.0000x reference)
//
#include <hip/hip_runtime.h>

#define NB_ 3
#define CB 4
#define CH 1440
#define CW 1440
#define NC 32
#define EPSV 1e-3f

#define HBITS 19
#define HSIZE (1u << HBITS)
#define HMASK (HSIZE - 1)

typedef __attribute__((ext_vector_type(8))) short bf16x8;
typedef __attribute__((ext_vector_type(16))) float f32x16;

union U16 { uint4 u; bf16x8 v; };

__device__ __forceinline__ unsigned pk2(float a, float b) {
    unsigned ua = __float_as_uint(a), ub = __float_as_uint(b);
    ua += 0x7fffu + ((ua >> 16) & 1u);
    ub += 0x7fffu + ((ub >> 16) & 1u);
    return (ua >> 16) | (ub & 0xffff0000u);
}
__device__ __forceinline__ unsigned short f2b(float a) {
    unsigned u = __float_as_uint(a);
    u += 0x7fffu + ((u >> 16) & 1u);
    return (unsigned short)(u >> 16);
}
__device__ __forceinline__ float b2f(unsigned short s) {
    return __uint_as_float(((unsigned)s) << 16);
}

__device__ __forceinline__ unsigned hash_of(unsigned key) {
    return (key * 2654435761u) >> (32 - HBITS);
}

// ---------------- kernel 1: hash insert (CAS claim + max-idx = last-write-wins) ----
__global__ __launch_bounds__(256) void k_hinsert(
    const int* __restrict__ cb, const int* __restrict__ cy, const int* __restrict__ cx,
    unsigned long long* __restrict__ tab, int n)
{
    int i = blockIdx.x * blockDim.x + threadIdx.x;
    if (i >= n) return;
    unsigned key = ((unsigned)cb[i] * CH + (unsigned)cy[i]) * CW + (unsigned)cx[i];
    unsigned long long pk = (((unsigned long long)(key + 1)) << 32) | (unsigned)i;
    unsigned h = hash_of(key);
    for (;;) {
        unsigned long long old = atomicCAS(&tab[h], 0ull, pk);
        if (old == 0ull) break;
        if ((unsigned)(old >> 32) == key + 1) { atomicMax(&tab[h], pk); break; }
        h = (h + 1) & HMASK;
    }
}

__device__ __forceinline__ int hquery(const unsigned long long* __restrict__ tab,
                                      unsigned key)
{
    unsigned h = hash_of(key);
    for (;;) {
        unsigned long long v = tab[h];
        if (v == 0ull) return -1;
        if ((unsigned)(v >> 32) == key + 1) return (int)(v & 0xffffffffu);
        h = (h + 1) & HMASK;
    }
}

// ---------------- kernel 2 (fused): rulebook + feats->bf16 + W->B-frags ------------
// Block-range split: [0,RB) rulebook, [RB,RB+CVT) cvt, [RB+CVT,RB+CVT+27) wcvt.
__global__ __launch_bounds__(256) void k_prep(
    const int* __restrict__ cb, const int* __restrict__ cy, const int* __restrict__ cx,
    const unsigned long long* __restrict__ tab, int* __restrict__ roff,
    const float* __restrict__ feats, unsigned short* __restrict__ xbf,
    const float* __restrict__ Wk, uint4* __restrict__ Bfg,
    unsigned short* __restrict__ z0, unsigned short* __restrict__ z1,
    unsigned short* __restrict__ z2, int n)
{
    int RB = (n + 255) >> 8;
    int CVT = ((n * NC / 8) + 255) >> 8;
    int bx = blockIdx.x;

    if (bx < RB) {                       // ---- rulebook: roff[9][n] byte offsets ----
        int i = bx * 256 + threadIdx.x;
        if (i >= n) return;
        int b = cb[i], y = cy[i], x = cx[i];
        unsigned key = ((unsigned)b * CH + (unsigned)y) * CW + (unsigned)x;
        roff[4 * n + i] = hquery(tab, key) * 64;          // self winner, always >=0
        #pragma unroll
        for (int k = 0; k < 9; ++k) {
            if (k == 4) continue;
            int dy = k / 3 - 1, dx = k % 3 - 1;
            int ny = y + dy, nx = x + dx;
            int nb = -1;
            if (ny >= 0 && ny < CH && nx >= 0 && nx < CW)
                nb = hquery(tab, key + dy * CW + dx);
            roff[k * n + i] = (nb >= 0) ? nb * 64 : -1;
        }
    } else if (bx < RB + CVT) {          // ---- feats f32 -> bf16 --------------------
        int i = ((bx - RB) * 256 + threadIdx.x) * 8;
        if (i + 8 <= n * NC) {
            float4 a0 = *(const float4*)(feats + i);
            float4 a1 = *(const float4*)(feats + i + 4);
            uint4 r;
            r.x = pk2(a0.x, a0.y); r.y = pk2(a0.z, a0.w);
            r.z = pk2(a1.x, a1.y); r.w = pk2(a1.z, a1.w);
            *(uint4*)(xbf + i) = r;
        }
    } else {                             // ---- W -> bf16 B-frags + zero rows --------
        int wb = bx - RB - CVT;
        if (wb == 0 && threadIdx.x < 12) {
            uint4 z = make_uint4(0, 0, 0, 0);
            int tt = threadIdx.x;
            if (tt < 4)       ((uint4*)z0)[tt] = z;
            else if (tt < 8)  ((uint4*)z1)[tt - 4] = z;
            else              ((uint4*)z2)[tt - 8] = z;
        }
        int t = wb * 256 + threadIdx.x;
        if (t >= 6 * 9 * 2 * 64) return;
        int l = t & 63, h = (t >> 6) & 1;
        int rest = t >> 7;
        int k = rest % 9, layer = rest / 9;
        int o = l & 31;
        int c0 = h * 16 + 8 * (l >> 5);
        const float* wp = Wk + (size_t)layer * 9216 + k * 1024 + o;   // [c][o]
        uint4 r;
        r.x = pk2(wp[(c0 + 0) * 32], wp[(c0 + 1) * 32]);
        r.y = pk2(wp[(c0 + 2) * 32], wp[(c0 + 3) * 32]);
        r.z = pk2(wp[(c0 + 4) * 32], wp[(c0 + 5) * 32]);
        r.w = pk2(wp[(c0 + 6) * 32], wp[(c0 + 7) * 32]);
        Bfg[t] = r;
    }
}

// ---------------- kernel 4: gather-K 32x32x16 MFMA conv + BN (+identity) + ReLU ----
// (r11 body, unchanged: one wave = one 32-pt tile, single pass, bound (256,6).)
template<bool ADD_ID, bool F32OUT>
__global__ __launch_bounds__(256, 6) void k_conv(
    const unsigned short* __restrict__ in,   // bf16 [n+1][32], row n = zeros
    const unsigned short* __restrict__ idn,  // bf16 [n][32]
    void* __restrict__ outv,                 // bf16 or f32 [n][32]
    const uint4* __restrict__ Bf,            // [9][2][64] B-frags (this layer)
    const float* __restrict__ bias,
    const float* __restrict__ gamma, const float* __restrict__ beta,
    const float* __restrict__ mean, const float* __restrict__ var,
    const int* __restrict__ roff, int n)
{
    int l = threadIdx.x & 63, wv = threadIdx.x >> 6;
    int q = l & 31, h5 = l >> 5;

    int ntile = (n + 31) >> 5;
    int tile = blockIdx.x * 4 + wv;
    if (tile >= ntile) return;

    float sc = gamma[q] * rsqrtf(var[q] + EPSV);
    float sh = (bias[q] - mean[q]) * sc + beta[q];

    const int zoff = n * 64;
    const char* inB = (const char*)in;

    int p0 = tile << 5;
    int pr = p0 + q;
    bool rowok = pr < n;
    int prc = rowok ? pr : n - 1;

    int rk[9];
    #pragma unroll
    for (int k = 0; k < 9; ++k) rk[k] = roff[(size_t)k * n + prc];

    f32x16 acc = {0.f,0.f,0.f,0.f,0.f,0.f,0.f,0.f,0.f,0.f,0.f,0.f,0.f,0.f,0.f,0.f};

    #pragma unroll
    for (int g = 0; g < 3; ++g) {
        bool act[3];
        U16 a0[3], a1[3];
        #pragma unroll
        for (int j = 0; j < 3; ++j) {
            int k = g * 3 + j;
            act[j] = __any(rk[k] >= 0);
            if (act[j]) {
                int off = (rowok && rk[k] >= 0) ? rk[k] : zoff;
                const char* ap = inB + off + h5 * 16;
                a0[j].u = *(const uint4*)(ap);        // chans h5*8    ..+8 (K-half 0)
                a1[j].u = *(const uint4*)(ap + 32);   // chans 16+h5*8 ..+8 (K-half 1)
            }
        }
        #pragma unroll
        for (int j = 0; j < 3; ++j) {
            int k = g * 3 + j;
            if (act[j]) {
                U16 b0, b1;
                b0.u = Bf[(k * 2 + 0) * 64 + l];
                b1.u = Bf[(k * 2 + 1) * 64 + l];
                acc = __builtin_amdgcn_mfma_f32_32x32x16_bf16(a0[j].v, b0.v, acc, 0, 0, 0);
                acc = __builtin_amdgcn_mfma_f32_32x32x16_bf16(a1[j].v, b1.v, acc, 0, 0, 0);
            }
        }
    }

    #pragma unroll
    for (int r = 0; r < 16; ++r) {
        int p = p0 + (r & 3) + 8 * (r >> 2) + 4 * h5;
        if (p < n) {
            float y = acc[r] * sc + sh;
            if (ADD_ID) y += b2f(idn[(size_t)p * 32 + q]);
            y = fmaxf(y, 0.f);
            if (F32OUT) ((float*)outv)[(size_t)p * 32 + q] = y;
            else ((unsigned short*)outv)[(size_t)p * 32 + q] = f2b(y);
        }
    }
}

extern "C" void kernel_launch(void* const* d_in, const int* in_sizes, int n_in,
                              void* d_out, int out_size, void* d_ws, size_t ws_size,
                              hipStream_t stream)
{
    const float* feats = (const float*)d_in[0];
    const float* Wk    = (const float*)d_in[1];  // [3][2][9][32][32]
    const float* bias  = (const float*)d_in[2];
    const float* gamma = (const float*)d_in[3];
    const float* beta  = (const float*)d_in[4];
    const float* mean  = (const float*)d_in[5];
    const float* var   = (const float*)d_in[6];
    const int* cb = (const int*)d_in[7];
    const int* cy = (const int*)d_in[8];
    const int* cx = (const int*)d_in[9];
    float* out = (float*)d_out;
    int n = in_sizes[0] / NC;

    char* ws = (char*)d_ws;
    unsigned long long* tab  = (unsigned long long*)(ws + 0);   //  4,194,304 B
    int*            roff     = (int*)(ws + 4194304);            //  7,200,000 B
    uint4*          Bfg      = (uint4*)(ws + 11394304);         //    110,592 B
    unsigned short* xbf      = (unsigned short*)(ws + 11504896); // 12,800,064 B
    unsigned short* tmpbf    = (unsigned short*)(ws + 24304960); // 12,800,064 B
    unsigned short* hb       = (unsigned short*)(ws + 37105024); // 12,800,064 B

    hipMemsetAsync(tab, 0, (size_t)HSIZE * 8, stream);

    int RB  = (n + 255) / 256;
    int CVT = ((n * NC / 8) + 255) / 256;
    k_hinsert<<<RB, 256, 0, stream>>>(cb, cy, cx, tab, n);
    k_prep<<<RB + CVT + 27, 256, 0, stream>>>(
        cb, cy, cx, tab, roff, feats, xbf, Wk, Bfg,
        xbf + (size_t)n * 32, tmpbf + (size_t)n * 32, hb + (size_t)n * 32, n);

    const int ntile = (n + 31) / 32;
    const int G = (ntile + 3) / 4;   // one tile per wave, single pass
    const int BSZ = 9 * 2 * 64;      // uint4s per layer of Bfg

    k_conv<false, false><<<G, 256, 0, stream>>>(xbf, nullptr, tmpbf,
        Bfg + 0 * BSZ, bias + 0,  gamma + 0,  beta + 0,  mean + 0,  var + 0,  roff, n);
    k_conv<true,  false><<<G, 256, 0, stream>>>(tmpbf, xbf, hb,
        Bfg + 1 * BSZ, bias + 32, gamma + 32, beta + 32, mean + 32, var + 32, roff, n);
    k_conv<false, false><<<G, 256, 0, stream>>>(hb, nullptr, tmpbf,
        Bfg + 2 * BSZ, bias + 64, gamma + 64, beta + 64, mean + 64, var + 64, roff, n);
    k_conv<true,  false><<<G, 256, 0, stream>>>(tmpbf, hb, xbf,
        Bfg + 3 * BSZ, bias + 96, gamma + 96, beta + 96, mean + 96, var + 96, roff, n);
    k_conv<false, false><<<G, 256, 0, stream>>>(xbf, nullptr, tmpbf,
        Bfg + 4 * BSZ, bias + 128, gamma + 128, beta + 128, mean + 128, var + 128, roff, n);
    k_conv<true,  true><<<G, 256, 0, stream>>>(tmpbf, xbf, out,
        Bfg + 5 * BSZ, bias + 160, gamma + 160, beta + 160, mean + 160, var + 160, roff, n);
}

// Round 13
// 128.369 us; speedup vs baseline: 1.1025x; 1.1025x over previous
//
#include <hip/hip_runtime.h>

#define NB_ 3
#define CB 4
#define CH 1440
#define CW 1440
#define NC 32
#define EPSV 1e-3f

typedef __attribute__((ext_vector_type(8))) short bf16x8;
typedef __attribute__((ext_vector_type(16))) float f32x16;

union U16 { uint4 u; bf16x8 v; };

__device__ __forceinline__ unsigned pk2(float a, float b) {
    unsigned ua = __float_as_uint(a), ub = __float_as_uint(b);
    ua += 0x7fffu + ((ua >> 16) & 1u);
    ub += 0x7fffu + ((ub >> 16) & 1u);
    return (ua >> 16) | (ub & 0xffff0000u);
}
__device__ __forceinline__ unsigned short f2b(float a) {
    unsigned u = __float_as_uint(a);
    u += 0x7fffu + ((u >> 16) & 1u);
    return (unsigned short)(u >> 16);
}
__device__ __forceinline__ float b2f(unsigned short s) {
    return __uint_as_float(((unsigned)s) << 16);
}

// ---------------- kernel 0: clear ONLY center cells + emit packed keys -------------
// Neighbor cells are never cleared; rulebook verifies instead. Any multi-point cell
// is some point's own cell (always cleared+rebuilt); a non-point cell can never pass
// verification (no point has its key) -> garbage-safe incl. unpoisoned first call.
// Stale winners from prior replays == current winners (point set constant) and
// atomicMax is idempotent -> deterministic across replays.
__global__ __launch_bounds__(256) void k_clear(
    const int* __restrict__ cb, const int* __restrict__ cy, const int* __restrict__ cx,
    int* __restrict__ idx_map, unsigned* __restrict__ pkey, int n)
{
    int i = blockIdx.x * blockDim.x + threadIdx.x;
    if (i >= n) return;
    unsigned key = ((unsigned)cb[i] * CH + (unsigned)cy[i]) * CW + (unsigned)cx[i];
    pkey[i] = key;
    idx_map[key] = -1;
}

// ---------------- kernel 1: build idx_map via atomicMax (numpy last-write-wins) ----
__global__ __launch_bounds__(256) void k_build_map(
    const unsigned* __restrict__ pkey, int* __restrict__ idx_map, int n)
{
    int i = blockIdx.x * blockDim.x + threadIdx.x;
    if (i < n) atomicMax(&idx_map[pkey[i]], i);
}

__device__ __forceinline__ int vquery(const int* __restrict__ idx_map,
                                      const unsigned* __restrict__ pkey,
                                      unsigned cell, int n)
{
    int v = idx_map[cell];
    if (v < 0 || v >= n) return -1;
    return (pkey[v] == cell) ? v : -1;
}

// ---------------- kernel 2 (fused): rulebook + feats->bf16 + W->B-frags ------------
// Block-range split: [0,RB) rulebook, [RB,RB+CVT) cvt, [RB+CVT,RB+CVT+27) wcvt.
__global__ __launch_bounds__(256) void k_prep(
    const unsigned* __restrict__ pkey, const int* __restrict__ idx_map,
    int* __restrict__ roff,
    const float* __restrict__ feats, unsigned short* __restrict__ xbf,
    const float* __restrict__ Wk, uint4* __restrict__ Bfg,
    unsigned short* __restrict__ z0, unsigned short* __restrict__ z1,
    unsigned short* __restrict__ z2, int n)
{
    int RB = (n + 255) >> 8;
    int CVT = ((n * NC / 8) + 255) >> 8;
    int bx = blockIdx.x;

    if (bx < RB) {                       // ---- rulebook: roff[9][n] byte offsets ----
        int i = bx * 256 + threadIdx.x;
        if (i >= n) return;
        unsigned key = pkey[i];
        unsigned x = key % CW;
        unsigned y = (key / CW) % CH;
        roff[4 * n + i] = idx_map[key] * 64;   // own cell: cleared+built, trusted
        #pragma unroll
        for (int k = 0; k < 9; ++k) {
            if (k == 4) continue;
            int dy = k / 3 - 1, dx = k % 3 - 1;
            int ny = (int)y + dy, nx = (int)x + dx;
            int nb = -1;
            if (ny >= 0 && ny < CH && nx >= 0 && nx < CW)
                nb = vquery(idx_map, pkey, key + dy * CW + dx, n);
            roff[k * n + i] = (nb >= 0) ? nb * 64 : -1;
        }
    } else if (bx < RB + CVT) {          // ---- feats f32 -> bf16 --------------------
        int i = ((bx - RB) * 256 + threadIdx.x) * 8;
        if (i + 8 <= n * NC) {
            float4 a0 = *(const float4*)(feats + i);
            float4 a1 = *(const float4*)(feats + i + 4);
            uint4 r;
            r.x = pk2(a0.x, a0.y); r.y = pk2(a0.z, a0.w);
            r.z = pk2(a1.x, a1.y); r.w = pk2(a1.z, a1.w);
            *(uint4*)(xbf + i) = r;
        }
    } else {                             // ---- W -> bf16 B-frags + zero rows --------
        int wb = bx - RB - CVT;
        if (wb == 0 && threadIdx.x < 12) {
            uint4 z = make_uint4(0, 0, 0, 0);
            int tt = threadIdx.x;
            if (tt < 4)       ((uint4*)z0)[tt] = z;
            else if (tt < 8)  ((uint4*)z1)[tt - 4] = z;
            else              ((uint4*)z2)[tt - 8] = z;
        }
        int t = wb * 256 + threadIdx.x;
        if (t >= 6 * 9 * 2 * 64) return;
        int l = t & 63, h = (t >> 6) & 1;
        int rest = t >> 7;
        int k = rest % 9, layer = rest / 9;
        int o = l & 31;
        int c0 = h * 16 + 8 * (l >> 5);
        const float* wp = Wk + (size_t)layer * 9216 + k * 1024 + o;   // [c][o]
        uint4 r;
        r.x = pk2(wp[(c0 + 0) * 32], wp[(c0 + 1) * 32]);
        r.y = pk2(wp[(c0 + 2) * 32], wp[(c0 + 3) * 32]);
        r.z = pk2(wp[(c0 + 4) * 32], wp[(c0 + 5) * 32]);
        r.w = pk2(wp[(c0 + 6) * 32], wp[(c0 + 7) * 32]);
        Bfg[t] = r;
    }
}

// ---------------- kernel 4: gather-K 32x32x16 MFMA conv + BN (+identity) + ReLU ----
// (r11 body, unchanged: one wave = one 32-pt tile, single pass, bound (256,6).)
template<bool ADD_ID, bool F32OUT>
__global__ __launch_bounds__(256, 6) void k_conv(
    const unsigned short* __restrict__ in,   // bf16 [n+1][32], row n = zeros
    const unsigned short* __restrict__ idn,  // bf16 [n][32]
    void* __restrict__ outv,                 // bf16 or f32 [n][32]
    const uint4* __restrict__ Bf,            // [9][2][64] B-frags (this layer)
    const float* __restrict__ bias,
    const float* __restrict__ gamma, const float* __restrict__ beta,
    const float* __restrict__ mean, const float* __restrict__ var,
    const int* __restrict__ roff, int n)
{
    int l = threadIdx.x & 63, wv = threadIdx.x >> 6;
    int q = l & 31, h5 = l >> 5;

    int ntile = (n + 31) >> 5;
    int tile = blockIdx.x * 4 + wv;
    if (tile >= ntile) return;

    float sc = gamma[q] * rsqrtf(var[q] + EPSV);
    float sh = (bias[q] - mean[q]) * sc + beta[q];

    const int zoff = n * 64;
    const char* inB = (const char*)in;

    int p0 = tile << 5;
    int pr = p0 + q;
    bool rowok = pr < n;
    int prc = rowok ? pr : n - 1;

    int rk[9];
    #pragma unroll
    for (int k = 0; k < 9; ++k) rk[k] = roff[(size_t)k * n + prc];

    f32x16 acc = {0.f,0.f,0.f,0.f,0.f,0.f,0.f,0.f,0.f,0.f,0.f,0.f,0.f,0.f,0.f,0.f};

    #pragma unroll
    for (int g = 0; g < 3; ++g) {
        bool act[3];
        U16 a0[3], a1[3];
        #pragma unroll
        for (int j = 0; j < 3; ++j) {
            int k = g * 3 + j;
            act[j] = __any(rk[k] >= 0);
            if (act[j]) {
                int off = (rowok && rk[k] >= 0) ? rk[k] : zoff;
                const char* ap = inB + off + h5 * 16;
                a0[j].u = *(const uint4*)(ap);        // chans h5*8    ..+8 (K-half 0)
                a1[j].u = *(const uint4*)(ap + 32);   // chans 16+h5*8 ..+8 (K-half 1)
            }
        }
        #pragma unroll
        for (int j = 0; j < 3; ++j) {
            int k = g * 3 + j;
            if (act[j]) {
                U16 b0, b1;
                b0.u = Bf[(k * 2 + 0) * 64 + l];
                b1.u = Bf[(k * 2 + 1) * 64 + l];
                acc = __builtin_amdgcn_mfma_f32_32x32x16_bf16(a0[j].v, b0.v, acc, 0, 0, 0);
                acc = __builtin_amdgcn_mfma_f32_32x32x16_bf16(a1[j].v, b1.v, acc, 0, 0, 0);
            }
        }
    }

    #pragma unroll
    for (int r = 0; r < 16; ++r) {
        int p = p0 + (r & 3) + 8 * (r >> 2) + 4 * h5;
        if (p < n) {
            float y = acc[r] * sc + sh;
            if (ADD_ID) y += b2f(idn[(size_t)p * 32 + q]);
            y = fmaxf(y, 0.f);
            if (F32OUT) ((float*)outv)[(size_t)p * 32 + q] = y;
            else ((unsigned short*)outv)[(size_t)p * 32 + q] = f2b(y);
        }
    }
}

extern "C" void kernel_launch(void* const* d_in, const int* in_sizes, int n_in,
                              void* d_out, int out_size, void* d_ws, size_t ws_size,
                              hipStream_t stream)
{
    const float* feats = (const float*)d_in[0];
    const float* Wk    = (const float*)d_in[1];  // [3][2][9][32][32]
    const float* bias  = (const float*)d_in[2];
    const float* gamma = (const float*)d_in[3];
    const float* beta  = (const float*)d_in[4];
    const float* mean  = (const float*)d_in[5];
    const float* var   = (const float*)d_in[6];
    const int* cb = (const int*)d_in[7];
    const int* cy = (const int*)d_in[8];
    const int* cx = (const int*)d_in[9];
    float* out = (float*)d_out;
    int n = in_sizes[0] / NC;

    char* ws = (char*)d_ws;
    int*            idx_map = (int*)(ws + 0);                   // 33,177,600 B
    unsigned*       pkey    = (unsigned*)(ws + 33177600);       //    800,000 B
    int*            roff    = (int*)(ws + 33977600);            //  7,200,000 B
    uint4*          Bfg     = (uint4*)(ws + 41177600);          //    110,592 B
    unsigned short* xbf     = (unsigned short*)(ws + 41288192); // 12,800,064 B
    unsigned short* tmpbf   = (unsigned short*)(ws + 54088256); // 12,800,064 B
    unsigned short* hb      = (unsigned short*)(ws + 66888320); // 12,800,064 B

    int RB  = (n + 255) / 256;
    int CVT = ((n * NC / 8) + 255) / 256;
    k_clear<<<RB, 256, 0, stream>>>(cb, cy, cx, idx_map, pkey, n);
    k_build_map<<<RB, 256, 0, stream>>>(pkey, idx_map, n);
    k_prep<<<RB + CVT + 27, 256, 0, stream>>>(
        pkey, idx_map, roff, feats, xbf, Wk, Bfg,
        xbf + (size_t)n * 32, tmpbf + (size_t)n * 32, hb + (size_t)n * 32, n);

    const int ntile = (n + 31) / 32;
    const int G = (ntile + 3) / 4;   // one tile per wave, single pass
    const int BSZ = 9 * 2 * 64;      // uint4s per layer of Bfg

    k_conv<false, false><<<G, 256, 0, stream>>>(xbf, nullptr, tmpbf,
        Bfg + 0 * BSZ, bias + 0,  gamma + 0,  beta + 0,  mean + 0,  var + 0,  roff, n);
    k_conv<true,  false><<<G, 256, 0, stream>>>(tmpbf, xbf, hb,
        Bfg + 1 * BSZ, bias + 32, gamma + 32, beta + 32, mean + 32, var + 32, roff, n);
    k_conv<false, false><<<G, 256, 0, stream>>>(hb, nullptr, tmpbf,
        Bfg + 2 * BSZ, bias + 64, gamma + 64, beta + 64, mean + 64, var + 64, roff, n);
    k_conv<true,  false><<<G, 256, 0, stream>>>(tmpbf, hb, xbf,
        Bfg + 3 * BSZ, bias + 96, gamma + 96, beta + 96, mean + 96, var + 96, roff, n);
    k_conv<false, false><<<G, 256, 0, stream>>>(xbf, nullptr, tmpbf,
        Bfg + 4 * BSZ, bias + 128, gamma + 128, beta + 128, mean + 128, var + 128, roff, n);
    k_conv<true,  true><<<G, 256, 0, stream>>>(tmpbf, xbf, out,
        Bfg + 5 * BSZ, bias + 160, gamma + 160, beta + 160, mean + 160, var + 160, roff, n);
}